// Round 6
// baseline (246.831 us; speedup 1.0000x reference)
//
#include <hip/hip_runtime.h>
#include <stdint.h>

// Problem constants (fixed by the reference)
#define BQ   2
#define NQ   8192
#define D1Q  128
#define D2Q  256
#define OUTQ 128
#define CATQ 384   // D1+D2
#define KQ   16

// ---------------------------------------------------------------------------
// Kernel 1: transpose W [OUT, CAT] -> Wt [CAT, OUT]  (tiny)
// ---------------------------------------------------------------------------
__global__ void wt_kernel(const float* __restrict__ W, float* __restrict__ Wt) {
    int flat = blockIdx.x * 256 + threadIdx.x;      // k*OUTQ + o
    if (flat < CATQ * OUTQ) {
        int k = flat >> 7;          // / OUTQ
        int o = flat & (OUTQ - 1);
        Wt[flat] = W[o * CATQ + k];
    }
}

// ---------------------------------------------------------------------------
// Kernel 1b: xyz1 norms, bit-exact numpy order.
// ---------------------------------------------------------------------------
__global__ void norm1_kernel(const float* __restrict__ xyz1,
                             float4* __restrict__ xyz1n) {
    int t = blockIdx.x * 256 + threadIdx.x;
    if (t < BQ * NQ) {
        float x = xyz1[t * 3 + 0];
        float y = xyz1[t * 3 + 1];
        float z = xyz1[t * 3 + 2];
        float n;
        {
            #pragma clang fp contract(off)
            float px = x * x, py = y * y, pz = z * z;
            n = (px + py) + pz;
        }
        xyz1n[t] = make_float4(x, y, z, n);
    }
}

// ---------------------------------------------------------------------------
// Kernel 2 (R6 rewrite): register-blocked GEMM.
// Block = 256 threads -> 64 rows x 128 cols. Thread = 8 rows x 4 cols.
// K in 6 chunks of 64 (2 from points1 -> P1Wb(+bias), 4 from points2 -> P2W),
// double-buffered LDS A-tile (reg-prefetch, one barrier per chunk).
// A reads: ds_read_b128 along k, wave-broadcast (32 lanes same addr) -> free.
// W reads: coalesced float4 of Wt[k][o0..o0+3] from L2 (192 KB, hot).
// Per-CU LDS issue: 4 waves x 96 chunks4 x 8 b128 x 12cyc ~= 37k cyc ~= 15us,
// overlapping the ~10us FMA floor.
// ---------------------------------------------------------------------------
__global__ __launch_bounds__(256) void proj_kernel(
        const float* __restrict__ points1, const float* __restrict__ points2,
        const float* __restrict__ Wt, const float* __restrict__ bias,
        float* __restrict__ P1Wb, float* __restrict__ P2W) {
    __shared__ __align__(16) float Al[2][64 * 64];   // 2 x 16 KB A tiles

    const int tid  = threadIdx.x;
    const int row0 = blockIdx.x * 64;
    const int rg   = tid >> 5;            // row group 0..7 (8 rows each)
    const int o0   = (tid & 31) * 4;      // output col base (float4 aligned)

    // staging geometry: flat = tid + 256*i (i<4); row = flat>>4, f4 = flat&15
    const int srow[4] = { (tid + 0) >> 4, (tid + 256) >> 4,
                          (tid + 512) >> 4, (tid + 768) >> 4 };
    const int sf4     = tid & 15;

    // chunk c in [0,6): c<2 -> points1 (ld=128), else points2 (ld=256)
    auto chunk_ptr = [&](int c, int r) -> const float4* {
        if (c < 2)
            return (const float4*)(points1 + (size_t)(row0 + r) * D1Q + c * 64)
                   + sf4;
        return (const float4*)(points2 + (size_t)(row0 + r) * D2Q + (c - 2) * 64)
               + sf4;
    };

    // prime chunk 0
    {
        float4 pre[4];
        #pragma unroll
        for (int i = 0; i < 4; ++i) pre[i] = *chunk_ptr(0, srow[i]);
        #pragma unroll
        for (int i = 0; i < 4; ++i)
            *(float4*)&Al[0][srow[i] * 64 + sf4 * 4] = pre[i];
    }
    __syncthreads();

    float4 acc[8];
    #pragma unroll
    for (int j = 0; j < 8; ++j) acc[j] = make_float4(0.f, 0.f, 0.f, 0.f);

    for (int c = 0; c < 6; ++c) {
        // prefetch next chunk to registers (global loads issue early)
        float4 pre[4];
        if (c + 1 < 6) {
            #pragma unroll
            for (int i = 0; i < 4; ++i) pre[i] = *chunk_ptr(c + 1, srow[i]);
        }

        const float* Ab = Al[c & 1];
        const int    kg0 = c * 64;
        #pragma unroll 4
        for (int k4 = 0; k4 < 16; ++k4) {
            const int kg = kg0 + k4 * 4;
            float4 w0 = *(const float4*)&Wt[(size_t)(kg + 0) * OUTQ + o0];
            float4 w1 = *(const float4*)&Wt[(size_t)(kg + 1) * OUTQ + o0];
            float4 w2 = *(const float4*)&Wt[(size_t)(kg + 2) * OUTQ + o0];
            float4 w3 = *(const float4*)&Wt[(size_t)(kg + 3) * OUTQ + o0];
            #pragma unroll
            for (int j = 0; j < 8; ++j) {
                float4 a = *(const float4*)&Ab[(rg * 8 + j) * 64 + k4 * 4];
                acc[j].x = fmaf(a.x, w0.x, acc[j].x);
                acc[j].y = fmaf(a.x, w0.y, acc[j].y);
                acc[j].z = fmaf(a.x, w0.z, acc[j].z);
                acc[j].w = fmaf(a.x, w0.w, acc[j].w);
                acc[j].x = fmaf(a.y, w1.x, acc[j].x);
                acc[j].y = fmaf(a.y, w1.y, acc[j].y);
                acc[j].z = fmaf(a.y, w1.z, acc[j].z);
                acc[j].w = fmaf(a.y, w1.w, acc[j].w);
                acc[j].x = fmaf(a.z, w2.x, acc[j].x);
                acc[j].y = fmaf(a.z, w2.y, acc[j].y);
                acc[j].z = fmaf(a.z, w2.z, acc[j].z);
                acc[j].w = fmaf(a.z, w2.w, acc[j].w);
                acc[j].x = fmaf(a.w, w3.x, acc[j].x);
                acc[j].y = fmaf(a.w, w3.y, acc[j].y);
                acc[j].z = fmaf(a.w, w3.z, acc[j].z);
                acc[j].w = fmaf(a.w, w3.w, acc[j].w);
            }
        }

        // pass-A boundary: store P1Wb(+bias), reset acc
        if (c == 1) {
            float4 bv = *(const float4*)&bias[o0];
            #pragma unroll
            for (int j = 0; j < 8; ++j) {
                float4 r = acc[j];
                r.x += bv.x; r.y += bv.y; r.z += bv.z; r.w += bv.w;
                *(float4*)&P1Wb[(size_t)(row0 + rg * 8 + j) * OUTQ + o0] = r;
                acc[j] = make_float4(0.f, 0.f, 0.f, 0.f);
            }
        }

        // write prefetched chunk into the other buffer, then barrier
        if (c + 1 < 6) {
            #pragma unroll
            for (int i = 0; i < 4; ++i)
                *(float4*)&Al[(c + 1) & 1][srow[i] * 64 + sf4 * 4] = pre[i];
        }
        __syncthreads();
    }

    #pragma unroll
    for (int j = 0; j < 8; ++j)
        *(float4*)&P2W[(size_t)(row0 + rg * 8 + j) * OUTQ + o0] = acc[j];
}

// numpy-exact squared distance (same rounding as the reference BLAS path)
__device__ __forceinline__ float npy_d2(float4 pt, float qx, float qy, float qz,
                                        float s2) {
    #pragma clang fp contract(off)
    float d0  = pt.x * qx;                 // rounded product
    float dot = fmaf(pt.y, qy, d0);        // explicit FMA chain
    dot       = fmaf(pt.z, qz, dot);
    float tt  = s2 + pt.w;                 // rounded add
    return tt - 2.0f * dot;                // 2*dot exact; rounded sub
}

// full ascending bitonic sort of one uint64 per lane across the wave
__device__ __forceinline__ uint64_t sort64(uint64_t x, int lane) {
    #pragma unroll
    for (int k = 2; k <= 64; k <<= 1) {
        #pragma unroll
        for (int j = k >> 1; j > 0; j >>= 1) {
            uint64_t p = __shfl_xor((unsigned long long)x, j, 64);
            bool keep_min = (((lane & j) == 0) == ((lane & k) == 0));
            bool pless    = p < x;
            x = (pless == keep_min) ? p : x;   // ties: same value either way
        }
    }
    return x;
}

// ---------------------------------------------------------------------------
// Kernel 3: fused 16-NN + weights + gather/combine (unchanged from R5).
// ---------------------------------------------------------------------------
__global__ __launch_bounds__(256) void fpn_kernel(
        const float4* __restrict__ xyz1n, const float* __restrict__ xyz2,
        const float* __restrict__ P1Wb, const float* __restrict__ P2W,
        float* __restrict__ out) {
    __shared__ __align__(16) float4 xyzt4[1024];     // 16 KB tile
    __shared__ uint64_t wball[4][128];               // 4 KB candidate spill

    const int tid   = threadIdx.x;
    const int lane  = tid & 63;
    const int w     = tid >> 6;
    const int qflat = blockIdx.x * 4 + w;    // 0..16383
    const int b     = qflat >> 13;           // / NQ

    const float* qp = xyz2 + (size_t)qflat * 3;
    const float qx = qp[0], qy = qp[1], qz = qp[2];
    float s2;
    {
        #pragma clang fp contract(off)
        float px = qx * qx, py = qy * qy, pz = qz * qz;
        s2 = (px + py) + pz;
    }

    const float4* xb = xyz1n + (size_t)b * NQ;

    // ---------------- Phase 1: branchless lane-min scan ----------------
    float mymin = __uint_as_float(0x7F800000u);   // +inf
    for (int tile = 0; tile < 8; ++tile) {
        __syncthreads();
        {
            const float4* s4 = xb + tile * 1024;
            #pragma unroll
            for (int v = tid; v < 1024; v += 256) xyzt4[v] = s4[v];
        }
        __syncthreads();
        #pragma unroll
        for (int s = 0; s < 16; ++s) {
            float4 pt = xyzt4[s * 64 + lane];
            mymin = fminf(mymin, npy_d2(pt, qx, qy, qz, s2));
        }
    }

    // bitonic sort of 64 lane minima; t_hat = rank 15
    {
        float x = mymin;
        #pragma unroll
        for (int k = 2; k <= 64; k <<= 1) {
            #pragma unroll
            for (int j = k >> 1; j > 0; j >>= 1) {
                float px = __shfl_xor(x, j, 64);
                bool keep_min = (((lane & j) == 0) == ((lane & k) == 0));
                float mn = fminf(x, px), mx = fmaxf(x, px);
                x = keep_min ? mn : mx;
            }
        }
        mymin = x;
    }
    const float that = __shfl(mymin, 15, 64);    // wave-uniform threshold

    // ---------------- Phase 2: branchless candidate compaction ----------------
    uint64_t* wbuf = wball[w];
    uint32_t  cnt  = 0;
    // tile 7 is still resident in LDS from phase 1 -> scan it first, no restage
    for (int tt = 0; tt < 8; ++tt) {
        const int tile = 7 - tt;
        if (tt > 0) {
            __syncthreads();
            const float4* s4 = xb + tile * 1024;
            #pragma unroll
            for (int v = tid; v < 1024; v += 256) xyzt4[v] = s4[v];
            __syncthreads();
        }
        const uint32_t base = (uint32_t)tile * 1024u;
        #pragma unroll
        for (int s = 0; s < 16; ++s) {
            float4 pt = xyzt4[s * 64 + lane];
            float  d2 = npy_d2(pt, qx, qy, qz, s2);
            bool   v  = (d2 <= that);
            uint64_t mask = __ballot((int)v);
            uint32_t below = __builtin_amdgcn_mbcnt_hi(
                                 (uint32_t)(mask >> 32),
                                 __builtin_amdgcn_mbcnt_lo((uint32_t)mask, 0u));
            uint32_t pos = cnt + below;
            if (v && pos < 128u) {
                uint32_t bits   = __float_as_uint(d2);
                uint32_t mapped = bits ^ (0x80000000u |
                                  (uint32_t)((int32_t)bits >> 31));
                wbuf[pos] = ((uint64_t)mapped << 32) |
                            (uint64_t)(base + (uint32_t)(s * 64 + lane));
            }
            cnt += (uint32_t)__popcll(mask);
        }
    }

    // ---------------- Selection: bitonic top-16 ----------------
    uint64_t mykey;
    if (cnt <= 64u) {                                  // normal path
        uint64_t k0 = (lane < (int)cnt) ? wbuf[lane] : ~0ull;
        mykey = sort64(k0, lane);
    } else {                                           // uniform fallback
        uint32_t cc = cnt > 128u ? 128u : cnt;
        uint64_t k0 = wbuf[lane];                      // lanes 0..63 valid
        uint64_t k1 = (lane + 64 < (int)cc) ? wbuf[lane + 64] : ~0ull;
        k0 = sort64(k0, lane);
        k1 = sort64(k1, lane);
        uint64_t t1 = __shfl((unsigned long long)k1, lane & 15, 64);
        uint64_t km = (lane < 16) ? k0 : ((lane < 32) ? t1 : ~0ull);
        mykey = sort64(km, lane);
    }

    // ---- inverse-distance weights (lanes 0..15 hold the 16 NN) ----
    uint32_t mhi   = (uint32_t)(mykey >> 32);
    uint32_t rbits = (mhi & 0x80000000u) ? (mhi ^ 0x80000000u) : ~mhi;
    float    d2w   = __uint_as_float(rbits);
    int      myidx = (int)(uint32_t)(mykey & 0xFFFFFFFFull);
    float recip = (lane < KQ) ? (1.0f / (d2w + 1e-8f)) : 0.0f;
    float tot = recip;
    #pragma unroll
    for (int sh = 1; sh < 64; sh <<= 1) tot += __shfl_xor(tot, sh, 64);
    float wgt = recip / tot;

    // ---- fused gather + combine ----
    const float* prow = P1Wb + (size_t)qflat * OUTQ;
    float acc0 = prow[lane];
    float acc1 = prow[lane + 64];
    const float* p2b = P2W + (size_t)b * NQ * OUTQ;
    #pragma unroll
    for (int k = 0; k < KQ; ++k) {
        int   kk = __shfl(myidx, k, 64);
        float wk = __shfl(wgt,   k, 64);
        const float* row = p2b + (size_t)kk * OUTQ;
        acc0 = fmaf(wk, row[lane],      acc0);
        acc1 = fmaf(wk, row[lane + 64], acc1);
    }
    float* orow = out + (size_t)qflat * OUTQ;
    orow[lane]      = acc0;
    orow[lane + 64] = acc1;
}

// ---------------------------------------------------------------------------
// Launch
// ---------------------------------------------------------------------------
extern "C" void kernel_launch(void* const* d_in, const int* in_sizes, int n_in,
                              void* d_out, int out_size, void* d_ws, size_t ws_size,
                              hipStream_t stream) {
    const float* xyz1    = (const float*)d_in[0];
    const float* xyz2    = (const float*)d_in[1];
    const float* points1 = (const float*)d_in[2];
    const float* points2 = (const float*)d_in[3];
    const float* W       = (const float*)d_in[4];
    const float* bias    = (const float*)d_in[5];

    float* wsf  = (float*)d_ws;
    float* Wt   = wsf;                         // 384*128   = 49152 floats
    float* P1Wb = wsf + 49152;                 // 16384*128 = 2097152 floats
    float* P2W  = P1Wb + 2097152;              // 16384*128
    float4* xyz1n = (float4*)(P2W + 2097152);  // 16384 float4

    wt_kernel<<<(CATQ * OUTQ + 255) / 256, 256, 0, stream>>>(W, Wt);
    norm1_kernel<<<(BQ * NQ + 255) / 256, 256, 0, stream>>>(xyz1, xyz1n);
    proj_kernel<<<(BQ * NQ) / 64, 256, 0, stream>>>(points1, points2, Wt, bias, P1Wb, P2W);
    fpn_kernel<<<(BQ * NQ) / 4, 256, 0, stream>>>(xyz1n, xyz2, P1Wb, P2W, (float*)d_out);
}

// Round 7
// 203.851 us; speedup vs baseline: 1.2108x; 1.2108x over previous
//
#include <hip/hip_runtime.h>
#include <stdint.h>

// Problem constants (fixed by the reference)
#define BQ   2
#define NQ   8192
#define D1Q  128
#define D2Q  256
#define OUTQ 128
#define CATQ 384   // D1+D2
#define KQ   16

// ---------------------------------------------------------------------------
// Kernel 1: transpose W [OUT, CAT] -> Wt [CAT, OUT]  (tiny)
// ---------------------------------------------------------------------------
__global__ void wt_kernel(const float* __restrict__ W, float* __restrict__ Wt) {
    int flat = blockIdx.x * 256 + threadIdx.x;      // k*OUTQ + o
    if (flat < CATQ * OUTQ) {
        int k = flat >> 7;          // / OUTQ
        int o = flat & (OUTQ - 1);
        Wt[flat] = W[o * CATQ + k];
    }
}

// ---------------------------------------------------------------------------
// Kernel 1b: xyz1 norms, bit-exact numpy order.
// ---------------------------------------------------------------------------
__global__ void norm1_kernel(const float* __restrict__ xyz1,
                             float4* __restrict__ xyz1n) {
    int t = blockIdx.x * 256 + threadIdx.x;
    if (t < BQ * NQ) {
        float x = xyz1[t * 3 + 0];
        float y = xyz1[t * 3 + 1];
        float z = xyz1[t * 3 + 2];
        float n;
        {
            #pragma clang fp contract(off)
            float px = x * x, py = y * y, pz = z * z;
            n = (px + py) + pz;
        }
        xyz1n[t] = make_float4(x, y, z, n);
    }
}

__device__ __forceinline__ void fma4(float4& acc, float a, const float4& w) {
    acc.x = fmaf(a, w.x, acc.x);
    acc.y = fmaf(a, w.y, acc.y);
    acc.z = fmaf(a, w.z, acc.z);
    acc.w = fmaf(a, w.w, acc.w);
}

// ---------------------------------------------------------------------------
// Kernel 2 (R7): cache-streaming register GEMM. NO LDS.
// Block = 256 threads -> 32 rows x 128 cols; thread = 4 rows x 4 cols.
// Grid = 512 blocks = 2 blocks/CU (R6 lesson: 1 block/CU starves latency
// hiding). A-reads: wave-broadcast float4 (lanes 0-31 same addr). W-reads:
// coalesced float4 from L2-resident Wt (196 KB). Per k4: 8 VMEM vs 64 FMA.
// ---------------------------------------------------------------------------
__global__ __launch_bounds__(256) void proj_kernel(
        const float* __restrict__ points1, const float* __restrict__ points2,
        const float* __restrict__ Wt, const float* __restrict__ bias,
        float* __restrict__ P1Wb, float* __restrict__ P2W) {
    const int tid  = threadIdx.x;
    const int row0 = blockIdx.x * 32;
    const int rg   = tid >> 5;            // 0..7 -> rows rg*4 .. rg*4+3
    const int o0   = (tid & 31) * 4;      // output col base
    const int r0   = row0 + rg * 4;

    float4 acc[4];
    #pragma unroll
    for (int i = 0; i < 4; ++i) acc[i] = make_float4(0.f, 0.f, 0.f, 0.f);

    // ---- pass A: K=128 from points1 -> P1Wb (+bias) ----
    {
        const float* a0 = points1 + (size_t)(r0 + 0) * D1Q;
        const float* a1 = points1 + (size_t)(r0 + 1) * D1Q;
        const float* a2 = points1 + (size_t)(r0 + 2) * D1Q;
        const float* a3 = points1 + (size_t)(r0 + 3) * D1Q;
        #pragma unroll 2
        for (int k4 = 0; k4 < 32; ++k4) {
            const float* wbase = Wt + (size_t)(k4 * 4) * OUTQ + o0;
            float4 w0 = *(const float4*)(wbase + 0 * OUTQ);
            float4 w1 = *(const float4*)(wbase + 1 * OUTQ);
            float4 w2 = *(const float4*)(wbase + 2 * OUTQ);
            float4 w3 = *(const float4*)(wbase + 3 * OUTQ);
            float4 av0 = *(const float4*)(a0 + k4 * 4);
            float4 av1 = *(const float4*)(a1 + k4 * 4);
            float4 av2 = *(const float4*)(a2 + k4 * 4);
            float4 av3 = *(const float4*)(a3 + k4 * 4);
            fma4(acc[0], av0.x, w0); fma4(acc[0], av0.y, w1);
            fma4(acc[0], av0.z, w2); fma4(acc[0], av0.w, w3);
            fma4(acc[1], av1.x, w0); fma4(acc[1], av1.y, w1);
            fma4(acc[1], av1.z, w2); fma4(acc[1], av1.w, w3);
            fma4(acc[2], av2.x, w0); fma4(acc[2], av2.y, w1);
            fma4(acc[2], av2.z, w2); fma4(acc[2], av2.w, w3);
            fma4(acc[3], av3.x, w0); fma4(acc[3], av3.y, w1);
            fma4(acc[3], av3.z, w2); fma4(acc[3], av3.w, w3);
        }
        float4 bv = *(const float4*)(bias + o0);
        #pragma unroll
        for (int i = 0; i < 4; ++i) {
            float4 r = acc[i];
            r.x += bv.x; r.y += bv.y; r.z += bv.z; r.w += bv.w;
            *(float4*)&P1Wb[(size_t)(r0 + i) * OUTQ + o0] = r;
            acc[i] = make_float4(0.f, 0.f, 0.f, 0.f);
        }
    }

    // ---- pass B: K=256 from points2 -> P2W ----
    {
        const float* a0 = points2 + (size_t)(r0 + 0) * D2Q;
        const float* a1 = points2 + (size_t)(r0 + 1) * D2Q;
        const float* a2 = points2 + (size_t)(r0 + 2) * D2Q;
        const float* a3 = points2 + (size_t)(r0 + 3) * D2Q;
        #pragma unroll 2
        for (int k4 = 0; k4 < 64; ++k4) {
            const float* wbase = Wt + (size_t)(D1Q + k4 * 4) * OUTQ + o0;
            float4 w0 = *(const float4*)(wbase + 0 * OUTQ);
            float4 w1 = *(const float4*)(wbase + 1 * OUTQ);
            float4 w2 = *(const float4*)(wbase + 2 * OUTQ);
            float4 w3 = *(const float4*)(wbase + 3 * OUTQ);
            float4 av0 = *(const float4*)(a0 + k4 * 4);
            float4 av1 = *(const float4*)(a1 + k4 * 4);
            float4 av2 = *(const float4*)(a2 + k4 * 4);
            float4 av3 = *(const float4*)(a3 + k4 * 4);
            fma4(acc[0], av0.x, w0); fma4(acc[0], av0.y, w1);
            fma4(acc[0], av0.z, w2); fma4(acc[0], av0.w, w3);
            fma4(acc[1], av1.x, w0); fma4(acc[1], av1.y, w1);
            fma4(acc[1], av1.z, w2); fma4(acc[1], av1.w, w3);
            fma4(acc[2], av2.x, w0); fma4(acc[2], av2.y, w1);
            fma4(acc[2], av2.z, w2); fma4(acc[2], av2.w, w3);
            fma4(acc[3], av3.x, w0); fma4(acc[3], av3.y, w1);
            fma4(acc[3], av3.z, w2); fma4(acc[3], av3.w, w3);
        }
        #pragma unroll
        for (int i = 0; i < 4; ++i)
            *(float4*)&P2W[(size_t)(r0 + i) * OUTQ + o0] = acc[i];
    }
}

// numpy-exact squared distance (same rounding as the reference BLAS path)
__device__ __forceinline__ float npy_d2(float4 pt, float qx, float qy, float qz,
                                        float s2) {
    #pragma clang fp contract(off)
    float d0  = pt.x * qx;                 // rounded product
    float dot = fmaf(pt.y, qy, d0);        // explicit FMA chain
    dot       = fmaf(pt.z, qz, dot);
    float tt  = s2 + pt.w;                 // rounded add
    return tt - 2.0f * dot;                // 2*dot exact; rounded sub
}

// full ascending bitonic sort of one uint64 per lane across the wave
__device__ __forceinline__ uint64_t sort64(uint64_t x, int lane) {
    #pragma unroll
    for (int k = 2; k <= 64; k <<= 1) {
        #pragma unroll
        for (int j = k >> 1; j > 0; j >>= 1) {
            uint64_t p = __shfl_xor((unsigned long long)x, j, 64);
            bool keep_min = (((lane & j) == 0) == ((lane & k) == 0));
            bool pless    = p < x;
            x = (pless == keep_min) ? p : x;   // ties: same value either way
        }
    }
    return x;
}

// ---------------------------------------------------------------------------
// Kernel 3 (R7): fused 16-NN + weights + gather/combine.
// FOUR queries per wave: each ds_read_b128 of a point feeds 4 distance
// computations -> tile-read LDS issue per query cut 4x (the R6 bottleneck).
// Block = 256 threads = 4 waves = 16 queries. Grid = 1024 (4 blocks/CU).
// Phase 1: 4 lane-min scans + 4 float bitonics -> that[j] (rank-15 bound).
// Phase 2: ballot+mbcnt compaction per query, register counters,
//          branch-guarded ds_write (rare-taken).
// Selection: per-query sort64 (R5-proven key semantics, idx tie-break).
// Epilogue: v_readlane broadcasts (off DS pipe) + float2 gathers.
// ---------------------------------------------------------------------------
__global__ __launch_bounds__(256) void fpn_kernel(
        const float4* __restrict__ xyz1n, const float* __restrict__ xyz2,
        const float* __restrict__ P1Wb, const float* __restrict__ P2W,
        float* __restrict__ out) {
    __shared__ __align__(16) float4 xyzt4[1024];   // 16 KB tile
    __shared__ uint64_t wbuf[16][128];             // 16 KB candidate spill

    const int tid   = threadIdx.x;
    const int lane  = tid & 63;
    const int w     = tid >> 6;
    const int qbase = blockIdx.x * 16 + w * 4;     // wave's 4 queries
    const int b     = (blockIdx.x * 16) >> 13;     // uniform per block

    float qx[4], qy[4], qz[4], s2[4];
    #pragma unroll
    for (int j = 0; j < 4; ++j) {
        const float* qp = xyz2 + (size_t)(qbase + j) * 3;
        qx[j] = qp[0]; qy[j] = qp[1]; qz[j] = qp[2];
        {
            #pragma clang fp contract(off)
            float px = qx[j] * qx[j], py = qy[j] * qy[j], pz = qz[j] * qz[j];
            s2[j] = (px + py) + pz;
        }
    }

    const float4* xb = xyz1n + (size_t)b * NQ;

    // ---------------- Phase 1: branchless 4-query lane-min scan ----------------
    float mn[4];
    #pragma unroll
    for (int j = 0; j < 4; ++j) mn[j] = __uint_as_float(0x7F800000u);

    for (int tile = 0; tile < 8; ++tile) {
        __syncthreads();
        {
            const float4* s4 = xb + tile * 1024;
            #pragma unroll
            for (int v = tid; v < 1024; v += 256) xyzt4[v] = s4[v];
        }
        __syncthreads();
        #pragma unroll 4
        for (int s = 0; s < 16; ++s) {
            float4 pt = xyzt4[s * 64 + lane];
            #pragma unroll
            for (int j = 0; j < 4; ++j)
                mn[j] = fminf(mn[j], npy_d2(pt, qx[j], qy[j], qz[j], s2[j]));
        }
    }

    // 4 float bitonic sorts of lane minima; that[j] = rank 15 (provably safe)
    float that[4];
    #pragma unroll
    for (int j = 0; j < 4; ++j) {
        float x = mn[j];
        #pragma unroll
        for (int k = 2; k <= 64; k <<= 1) {
            #pragma unroll
            for (int jj = k >> 1; jj > 0; jj >>= 1) {
                float px = __shfl_xor(x, jj, 64);
                bool keep_min = (((lane & jj) == 0) == ((lane & k) == 0));
                float mnv = fminf(x, px), mxv = fmaxf(x, px);
                x = keep_min ? mnv : mxv;
            }
        }
        that[j] = __shfl(x, 15, 64);
    }

    // ---------------- Phase 2: compaction (register counters) ----------------
    uint32_t cnt[4] = {0u, 0u, 0u, 0u};
    for (int tt = 0; tt < 8; ++tt) {
        const int tile = 7 - tt;                   // tile 7 still resident
        if (tt > 0) {
            __syncthreads();
            const float4* s4 = xb + tile * 1024;
            #pragma unroll
            for (int v = tid; v < 1024; v += 256) xyzt4[v] = s4[v];
            __syncthreads();
        }
        const uint32_t base = (uint32_t)tile * 1024u;
        #pragma unroll 4
        for (int s = 0; s < 16; ++s) {
            float4 pt = xyzt4[s * 64 + lane];
            const uint32_t pidx = base + (uint32_t)(s * 64 + lane);
            #pragma unroll
            for (int j = 0; j < 4; ++j) {
                float d2 = npy_d2(pt, qx[j], qy[j], qz[j], s2[j]);
                bool  v  = (d2 <= that[j]);
                uint64_t mask = __ballot((int)v);
                if (v) {                           // rare-taken, guards ds_write
                    uint32_t below = __builtin_amdgcn_mbcnt_hi(
                        (uint32_t)(mask >> 32),
                        __builtin_amdgcn_mbcnt_lo((uint32_t)mask, 0u));
                    uint32_t pos    = cnt[j] + below;
                    uint32_t bits   = __float_as_uint(d2);
                    uint32_t mapped = bits ^ (0x80000000u |
                                      (uint32_t)((int32_t)bits >> 31));
                    if (pos < 128u)
                        wbuf[w * 4 + j][pos] =
                            ((uint64_t)mapped << 32) | (uint64_t)pidx;
                }
                cnt[j] += (uint32_t)__popcll(mask);
            }
        }
    }

    // ---------------- per-query selection + weights + gather ----------------
    const float* p2b = P2W + (size_t)b * NQ * OUTQ;
    #pragma unroll
    for (int j = 0; j < 4; ++j) {
        const int qi = w * 4 + j;
        const uint32_t c = cnt[j];
        uint64_t mykey;
        if (c <= 64u) {                            // normal path
            uint64_t k0 = (lane < (int)c) ? wbuf[qi][lane] : ~0ull;
            mykey = sort64(k0, lane);
        } else {                                   // uniform fallback
            uint32_t cc = c > 128u ? 128u : c;
            uint64_t k0 = wbuf[qi][lane];
            uint64_t k1 = (lane + 64 < (int)cc) ? wbuf[qi][lane + 64] : ~0ull;
            k0 = sort64(k0, lane);
            k1 = sort64(k1, lane);
            uint64_t t1 = __shfl((unsigned long long)k1, lane & 15, 64);
            uint64_t km = (lane < 16) ? k0 : ((lane < 32) ? t1 : ~0ull);
            mykey = sort64(km, lane);
        }

        // inverse-distance weights (lanes 0..15 hold the 16 NN)
        uint32_t mhi   = (uint32_t)(mykey >> 32);
        uint32_t rbits = (mhi & 0x80000000u) ? (mhi ^ 0x80000000u) : ~mhi;
        float    d2w   = __uint_as_float(rbits);
        int      myidx = (int)(uint32_t)(mykey & 0xFFFFFFFFull);
        float recip = (lane < KQ) ? (1.0f / (d2w + 1e-8f)) : 0.0f;
        float tot = recip;
        #pragma unroll
        for (int sh = 1; sh < 16; sh <<= 1) tot += __shfl_xor(tot, sh, 64);
        float wgt = recip / tot;                   // valid in lanes 0..15

        // gather + combine: out = P1Wb[q] + sum_k w_k * P2W[idx_k]
        const float2* prow = (const float2*)(P1Wb + (size_t)(qbase + j) * OUTQ);
        float2 acc = prow[lane];
        #pragma unroll
        for (int k = 0; k < KQ; ++k) {
            int   kk = __builtin_amdgcn_readlane(myidx, k);
            float wk = __uint_as_float((uint32_t)__builtin_amdgcn_readlane(
                           (int)__float_as_uint(wgt), k));
            const float2 row = *(const float2*)(p2b + (size_t)kk * OUTQ + lane * 2);
            acc.x = fmaf(wk, row.x, acc.x);
            acc.y = fmaf(wk, row.y, acc.y);
        }
        *(float2*)(out + (size_t)(qbase + j) * OUTQ + lane * 2) = acc;
    }
}

// ---------------------------------------------------------------------------
// Launch
// ---------------------------------------------------------------------------
extern "C" void kernel_launch(void* const* d_in, const int* in_sizes, int n_in,
                              void* d_out, int out_size, void* d_ws, size_t ws_size,
                              hipStream_t stream) {
    const float* xyz1    = (const float*)d_in[0];
    const float* xyz2    = (const float*)d_in[1];
    const float* points1 = (const float*)d_in[2];
    const float* points2 = (const float*)d_in[3];
    const float* W       = (const float*)d_in[4];
    const float* bias    = (const float*)d_in[5];

    float* wsf  = (float*)d_ws;
    float* Wt   = wsf;                         // 384*128   = 49152 floats
    float* P1Wb = wsf + 49152;                 // 16384*128 = 2097152 floats
    float* P2W  = P1Wb + 2097152;              // 16384*128
    float4* xyz1n = (float4*)(P2W + 2097152);  // 16384 float4

    wt_kernel<<<(CATQ * OUTQ + 255) / 256, 256, 0, stream>>>(W, Wt);
    norm1_kernel<<<(BQ * NQ + 255) / 256, 256, 0, stream>>>(xyz1, xyz1n);
    proj_kernel<<<(BQ * NQ) / 32, 256, 0, stream>>>(points1, points2, Wt, bias, P1Wb, P2W);
    fpn_kernel<<<(BQ * NQ) / 16, 256, 0, stream>>>(xyz1n, xyz2, P1Wb, P2W, (float*)d_out);
}